// Round 7
// baseline (9099.979 us; speedup 1.0000x reference)
//
#include <hip/hip_runtime.h>
#include <cstdint>
#include <cstddef>

// ---------------------------------------------------------------------------
// CTC-CRF BLSTM pipeline for MI355X.  B=64 T=1024 IDIM=120 HDIM=320 K=72
// den == 0 analytically; batch sort is a no-op under the batch mean. Skipped.
//
// R7 deltas vs R6 (9.03 ms):
//  - scan: fast sigmoid/tanh (v_exp+v_rcp, no libm), gx prefetch pipelined
//    one step ahead, and the partner-poll moved to threads 256-415 so it
//    runs CONCURRENTLY with the gate math on threads 0-159
//    (critical path = max(gates, RTT) instead of sum).
//  - gemm_chunk: 2 N-tiles per block (grid 5x128) -- halves A staging.
//  - ctc: depth-8 register-ring prefetch (t-loop unrolled x8), tail direct.
// ---------------------------------------------------------------------------

typedef _Float16 f16;
typedef _Float16 h2v   __attribute__((ext_vector_type(2)));
typedef _Float16 f16x8 __attribute__((ext_vector_type(8)));
typedef float    f32x4 __attribute__((ext_vector_type(4)));
typedef uint32_t u32x4 __attribute__((ext_vector_type(4)));

#define NEGF (-1e30f)
#define CT 128

__device__ __forceinline__ float dot2f(h2v a, h2v b, float c) {
#if __has_builtin(__builtin_amdgcn_fdot2)
  return __builtin_amdgcn_fdot2(a, b, c, false);
#else
  return c + (float)a.x * (float)b.x + (float)a.y * (float)b.y;
#endif
}

__device__ __forceinline__ float fast_rcp(float x) {
#if __has_builtin(__builtin_amdgcn_rcpf)
  return __builtin_amdgcn_rcpf(x);
#else
  return 1.f / x;
#endif
}
__device__ __forceinline__ float fsigm(float x) { return fast_rcp(1.f + __expf(-x)); }
__device__ __forceinline__ float ftanh(float x) { return 1.f - 2.f * fast_rcp(1.f + __expf(2.f * x)); }

__device__ __forceinline__ void stage16(f16* lds, const f16* g) {
#if __has_builtin(__builtin_amdgcn_global_load_lds)
  __builtin_amdgcn_global_load_lds(
      (const __attribute__((address_space(1))) uint32_t*)g,
      (__attribute__((address_space(3))) uint32_t*)lds, 16, 0, 0);
#else
  int lane = threadIdx.x & 63;
  *(f16x8*)&lds[lane * 8] = *(const f16x8*)g;
#endif
}

// ---------------------------- convert kernels ------------------------------

__global__ void conv_logits(const float* __restrict__ src, f16* __restrict__ dst) {
  int idx = blockIdx.x * 256 + threadIdx.x;      // < 65536*128
  int row = idx >> 7, k = idx & 127;
  dst[idx] = (f16)((k < 120) ? src[(size_t)row * 120 + k] : 0.f);
}

__global__ void conv_wt0(const float* __restrict__ w, f16* __restrict__ dst) {
  int idx = blockIdx.x * 256 + threadIdx.x;      // < 2560*128
  int n = idx >> 7, k = idx & 127;
  dst[idx] = (f16)((k < 120) ? w[(size_t)n * 120 + k] : 0.f);
}

__global__ void conv_copy(const float* __restrict__ src, f16* __restrict__ dst, int count) {
  int idx = blockIdx.x * 256 + threadIdx.x;
  if (idx < count) dst[idx] = (f16)src[idx];
}

__global__ void conv_wtl(const float* __restrict__ w, f16* __restrict__ dst) {
  int idx = blockIdx.x * 256 + threadIdx.x;      // < 128*640
  int n = idx / 640, k = idx % 640;
  dst[idx] = (f16)((n < 72) ? w[(size_t)n * 640 + k] : 0.f);
}

// Whh -> pair-packed scan layout (same as R6):
//   tau = i*512+tid; lr = tau>>2; kq = tau&3
//   gate = lr/160, u = lr%160 -> r = gate*320 + half*160 + u; k = kq*80 + 2j
__global__ void conv_whh(const float* __restrict__ whh0, const float* __restrict__ whh,
                         uint32_t* __restrict__ dst) {
  int o = blockIdx.x * 256 + threadIdx.x;        // < 6*2*200*512 = 1228800
  int tid = o & 511;
  int g  = o >> 9;
  int j  = g % 40;
  int g2 = g / 40;
  int i  = g2 % 5;
  int g3 = g2 / 5;                               // 0..11
  int hf = g3 & 1, slot = g3 >> 1;               // slot = layer*2+dir
  int tau = i * 512 + tid;
  int lr = tau >> 2, kq = tau & 3;
  int gate = lr / 160, u = lr - gate * 160;
  int r = gate * 320 + hf * 160 + u;
  int k = kq * 80 + j * 2;
  const float* srcm = (slot < 2) ? (whh0 + ((size_t)slot * 1280 + r) * 320)
                                 : (whh  + ((size_t)(slot - 2) * 1280 + r) * 320);
  f16 lo = (f16)srcm[k], hi = (f16)srcm[k + 1];
  dst[o] = (uint32_t)__builtin_bit_cast(unsigned short, lo) |
           ((uint32_t)__builtin_bit_cast(unsigned short, hi) << 16);
}

// --------------------- gather-GEMM for one time chunk ----------------------
// Grid (5, 128): 256-wide N-supertile (2 x 128), y = dir*64 + b. M = 128 steps.
__global__ __launch_bounds__(256)
void gemm_chunk(const f16* __restrict__ A, const f16* __restrict__ W,
                f16* __restrict__ gxc, const int* __restrict__ lens,
                int lda, int kTiles, int c0) {
  __shared__ __align__(16) f16 As[128 * 32];
  __shared__ __align__(16) f16 Ws[2][128 * 32];
  const int tid = threadIdx.x;
  const int lane = tid & 63, wid = tid >> 6;
  const int wm = wid >> 1, wn = wid & 1;
  const int dir = blockIdx.y >> 6, b = blockIdx.y & 63;
  const int n0 = blockIdx.x * 256;
  const int r_base = lane >> 2;
  const int c8 = (lane & 3) * 8;
  const int len = lens[b];

  f32x4 acc[4][8] = {};

  for (int kt = 0; kt < kTiles; ++kt) {
    const int k0 = kt * 32;
    __syncthreads();
#pragma unroll
    for (int hh = 0; hh < 2; ++hh) {
      const int c = wid * 2 + hh;
      const int j = c * 16 + r_base;                     // step within chunk
      const int s = c0 * CT + j;
      const int tt = dir ? ((s < len) ? (len - 1 - s) : s) : s;
      stage16(&As[c * 512], A + (size_t)(b * 1024 + tt) * lda + k0 + c8);
    }
#pragma unroll
    for (int hh = 0; hh < 4; ++hh) {
      const int c = wid * 4 + hh;                        // 0..15
      const int tile = c >> 3, cc = c & 7;
      stage16(&Ws[tile][cc * 512],
              W + (size_t)(dir * 1280 + n0 + tile * 128 + cc * 16 + r_base) * lda + k0 + c8);
    }
    __syncthreads();

    const int koff = (lane >> 4) * 8;
    f16x8 av[4], wv0[4], wv1[4];
#pragma unroll
    for (int i = 0; i < 4; ++i)
      av[i] = *(const f16x8*)&As[(wm * 64 + i * 16 + (lane & 15)) * 32 + koff];
#pragma unroll
    for (int i = 0; i < 4; ++i) {
      wv0[i] = *(const f16x8*)&Ws[0][(wn * 64 + i * 16 + (lane & 15)) * 32 + koff];
      wv1[i] = *(const f16x8*)&Ws[1][(wn * 64 + i * 16 + (lane & 15)) * 32 + koff];
    }
#pragma unroll
    for (int i = 0; i < 4; ++i)
#pragma unroll
      for (int j = 0; j < 4; ++j) {
        acc[i][j]     = __builtin_amdgcn_mfma_f32_16x16x32_f16(av[i], wv0[j], acc[i][j], 0, 0, 0);
        acc[i][4 + j] = __builtin_amdgcn_mfma_f32_16x16x32_f16(av[i], wv1[j], acc[i][4 + j], 0, 0, 0);
      }
  }

  const int r0 = (lane >> 4) * 4, cn = lane & 15;
  const size_t obase = (size_t)(dir * 64 + b) * CT;
#pragma unroll
  for (int i = 0; i < 4; ++i) {
    const int m = wm * 64 + i * 16 + r0;
#pragma unroll
    for (int j = 0; j < 4; ++j) {
      const int n = n0 + wn * 64 + j * 16 + cn;
#pragma unroll
      for (int r = 0; r < 4; ++r) {
        gxc[(obase + m + r) * 1280 + n]       = (f16)acc[i][j][r];
        gxc[(obase + m + r) * 1280 + n + 128] = (f16)acc[i][4 + j][r];
      }
    }
  }
}

// ------------------------- LSTM scan (one chunk) ---------------------------
// 256 WGs: wg = half*128 + (b*2+dir). Pair (wg, wg^128) = two 160-unit halves.
// Whh half (640x320 f16) register-resident (forced: waves_per_eu(2,2) +
// volatile loads + may-alias stores). Per step: all-thread dot -> B1 ->
// [0-159: gates+publish] CONCURRENT WITH [256-415: poll partner] -> B2.
__global__ void __launch_bounds__(512)
__attribute__((amdgpu_waves_per_eu(2, 2)))
lstm_scan_chunk(const volatile uint32_t* wbuf,      // NOT restrict: may alias
                const f16* __restrict__ gxc,        // [2*64*CT][1280]
                const float* __restrict__ bias,     // [2][1280] this layer
                const int* __restrict__ lens,
                f16* xnext,                         // [65536][640] (no restrict)
                uint32_t* xq,                       // [512][160] tagged words
                f16* hsave,                         // [128][320]
                float* csave,                       // [256][160]
                int layer, int c0) {
  const int wg = blockIdx.x;
  const int half = wg >> 7;
  const int bd = wg & 127;
  const int b = bd >> 1, dir = bd & 1;
  const int tid = threadIdx.x;

  __shared__ __align__(16) f16 hbuf[320];
  __shared__ float ylds[640];
  __shared__ __align__(16) f16 hstage[64 * 160];   // 20 KB ring

  h2v w[5][40];
  {
    const volatile uint32_t* wb =
        wbuf + (size_t)((layer * 2 + dir) * 2 + half) * 200 * 512;
#pragma unroll
    for (int i = 0; i < 5; ++i)
#pragma unroll
      for (int j = 0; j < 40; ++j) {
        uint32_t v = wb[(i * 40 + j) * 512 + tid];
        w[i][j] = __builtin_bit_cast(h2v, v);
      }
  }
  if (tid < 320) hbuf[tid] = (c0 == 0) ? (f16)0.f : hsave[bd * 320 + tid];

  const int len = lens[b];
  const int kq = tid & 3;
  const int qi = tid >> 2;
  const int gu = half * 160 + tid;               // valid when tid<160
  float c_state = 0.f;
  float bi = 0.f, bff = 0.f, bg = 0.f, bo = 0.f;
  if (tid < 160) {
    if (c0 > 0) c_state = csave[wg * 160 + tid];
    const float* bp = bias + dir * 1280 + gu;
    bi = bp[0]; bff = bp[320]; bg = bp[640]; bo = bp[960];
  }
  __syncthreads();

  const size_t grow0 = (size_t)(dir * 64 + b) * CT;

  // gx software pipeline: current regs + next regs
  float gxi = 0.f, gxf = 0.f, gxg = 0.f, gxo = 0.f;
  if (tid < 160) {
    const f16* gp = gxc + grow0 * 1280 + gu;
    gxi = (float)gp[0]; gxf = (float)gp[320]; gxg = (float)gp[640]; gxo = (float)gp[960];
  }

  for (int tl = 0; tl < CT; ++tl) {
    const int s = c0 * CT + tl;
    const uint32_t tag = (uint32_t)(layer * 1024 + s + 1);

    // issue next step's gx loads (land during dot+barrier)
    float nxi = 0.f, nxf = 0.f, nxg = 0.f, nxo = 0.f;
    if (tid < 160 && tl + 1 < CT) {
      const f16* gp = gxc + (grow0 + tl + 1) * 1280 + gu;
      nxi = (float)gp[0]; nxf = (float)gp[320]; nxg = (float)gp[640]; nxo = (float)gp[960];
    }

    // ---- y = Whh_half . h  (all threads, b128 LDS reads) ----
    float a0 = 0.f, a1 = 0.f, a2 = 0.f, a3 = 0.f, a4 = 0.f;
    {
      const u32x4* h4 = (const u32x4*)hbuf;      // 16B units (8 f16)
#pragma unroll
      for (int jb = 0; jb < 5; ++jb) {
        u32x4 p = h4[kq * 10 + jb * 2];
        u32x4 q = h4[kq * 10 + jb * 2 + 1];
        h2v hr[8];
#pragma unroll
        for (int j = 0; j < 4; ++j) hr[j] = __builtin_bit_cast(h2v, p[j]);
#pragma unroll
        for (int j = 0; j < 4; ++j) hr[4 + j] = __builtin_bit_cast(h2v, q[j]);
#pragma unroll
        for (int j = 0; j < 8; ++j) {
          a0 = dot2f(w[0][jb * 8 + j], hr[j], a0);
          a1 = dot2f(w[1][jb * 8 + j], hr[j], a1);
          a2 = dot2f(w[2][jb * 8 + j], hr[j], a2);
          a3 = dot2f(w[3][jb * 8 + j], hr[j], a3);
          a4 = dot2f(w[4][jb * 8 + j], hr[j], a4);
        }
      }
    }
    {
      float av[5] = {a0, a1, a2, a3, a4};
#pragma unroll
      for (int i = 0; i < 5; ++i) {
        float v = av[i];
        v += __shfl_xor(v, 1, 64);
        v += __shfl_xor(v, 2, 64);
        if (kq == 0) ylds[i * 128 + qi] = v;
      }
    }

    // every 32 steps: flush completed window of h to xnext (coalesced)
    if ((tl & 31) == 0 && tl > 0) {
      const int tw = tl - 32;
#pragma unroll
      for (int it = 0; it < 2; ++it) {
        const int slot = it * 512 + tid;
        if (slot < 640) {
          const int r = (int)(((unsigned)slot * 52429u) >> 20);  // slot/20
          const int j = slot - r * 20;
          const int sp = c0 * CT + tw + r;
          const int ttp = dir ? ((sp < len) ? (len - 1 - sp) : sp) : sp;
          f16x8 v = *(const f16x8*)&hstage[((tw + r) & 63) * 160 + j * 8];
          *(f16x8*)&xnext[(size_t)(b * 1024 + ttp) * 640 + dir * 320 + half * 160 + j * 8] = v;
        }
      }
    }
    __syncthreads();                              // B1: ylds ready

    if (tid < 160) {
      // gates (fast sigmoid/tanh; no libm)
      const int u = tid;
      float pi = ylds[u]       + gxi + bi;
      float pf = ylds[160 + u] + gxf + bff;
      float pg = ylds[320 + u] + gxg + bg;
      float po = ylds[480 + u] + gxo + bo;
      float ig = fsigm(pi);
      float fg = fsigm(pf);
      float gg = ftanh(pg);
      float og = fsigm(po);
      c_state = fg * c_state + ig * gg;
      float hv = og * ftanh(c_state);
      const f16 hh = (f16)hv;
      const uint32_t word = (tag << 16) |
                            (uint32_t)__builtin_bit_cast(unsigned short, hh);
      __hip_atomic_exchange(&xq[((bd * 2 + half) * 2 + (s & 1)) * 160 + u], word,
                            __ATOMIC_RELAXED, __HIP_MEMORY_SCOPE_AGENT);
      hbuf[gu] = hh;
      hstage[(tl & 63) * 160 + u] = hh;
    } else if (tid >= 256 && tid < 416) {
      // concurrent pollers (waves 4-6): receive partner h for this step
      const int u = tid - 256;
      uint32_t pw;
      int spins = 0;
      do {
        pw = __hip_atomic_fetch_add(&xq[((bd * 2 + (1 - half)) * 2 + (s & 1)) * 160 + u],
                                    0u, __ATOMIC_RELAXED, __HIP_MEMORY_SCOPE_AGENT);
      } while ((pw >> 16) != tag && ++spins < 30000);
      hbuf[(1 - half) * 160 + u] =
          __builtin_bit_cast(f16, (unsigned short)(pw & 0xffffu));
    }
    __syncthreads();                              // B2: hbuf ready for next dot

    gxi = nxi; gxf = nxf; gxg = nxg; gxo = nxo;
  }

  // final flush of last 32-step window
  {
    const int tw = CT - 32;
#pragma unroll
    for (int it = 0; it < 2; ++it) {
      const int slot = it * 512 + tid;
      if (slot < 640) {
        const int r = (int)(((unsigned)slot * 52429u) >> 20);
        const int j = slot - r * 20;
        const int sp = c0 * CT + tw + r;
        const int ttp = dir ? ((sp < len) ? (len - 1 - sp) : sp) : sp;
        f16x8 v = *(const f16x8*)&hstage[((tw + r) & 63) * 160 + j * 8];
        *(f16x8*)&xnext[(size_t)(b * 1024 + ttp) * 640 + dir * 320 + half * 160 + j * 8] = v;
      }
    }
  }
  if (tid < 160) {
    hsave[bd * 320 + gu] = hbuf[gu];
    csave[wg * 160 + tid] = c_state;
  }
}

// ---------------------- projection GEMM (f32 out) --------------------------
__global__ __launch_bounds__(256)
void gemm_proj(const f16* __restrict__ A, const f16* __restrict__ W,
               float* __restrict__ outf, int lda, int kTiles, int ldo) {
  __shared__ __align__(16) f16 As[128 * 32];
  __shared__ __align__(16) f16 Ws[128 * 32];
  const int tid = threadIdx.x;
  const int lane = tid & 63, wid = tid >> 6;
  const int wm = wid >> 1, wn = wid & 1;
  const int m0 = blockIdx.y * 128, n0 = blockIdx.x * 128;
  const int r_base = lane >> 2;
  const int c8 = (lane & 3) * 8;

  f32x4 acc[4][4] = {};

  for (int kt = 0; kt < kTiles; ++kt) {
    const int k0 = kt * 32;
    __syncthreads();
#pragma unroll
    for (int hh = 0; hh < 2; ++hh) {
      const int c = wid * 2 + hh;
      stage16(&As[c * 512], A + (size_t)(m0 + c * 16 + r_base) * lda + k0 + c8);
      stage16(&Ws[c * 512], W + (size_t)(n0 + c * 16 + r_base) * lda + k0 + c8);
    }
    __syncthreads();

    const int koff = (lane >> 4) * 8;
    f16x8 av[4], wv[4];
#pragma unroll
    for (int i = 0; i < 4; ++i)
      av[i] = *(const f16x8*)&As[(wm * 64 + i * 16 + (lane & 15)) * 32 + koff];
#pragma unroll
    for (int i = 0; i < 4; ++i)
      wv[i] = *(const f16x8*)&Ws[(wn * 64 + i * 16 + (lane & 15)) * 32 + koff];
#pragma unroll
    for (int i = 0; i < 4; ++i)
#pragma unroll
      for (int j = 0; j < 4; ++j)
        acc[i][j] = __builtin_amdgcn_mfma_f32_16x16x32_f16(av[i], wv[j], acc[i][j], 0, 0, 0);
  }

  const int r0 = (lane >> 4) * 4, cn = lane & 15;
#pragma unroll
  for (int i = 0; i < 4; ++i) {
    const int m = m0 + wm * 64 + i * 16 + r0;
#pragma unroll
    for (int j = 0; j < 4; ++j) {
      const int n = n0 + wn * 64 + j * 16 + cn;
#pragma unroll
      for (int r = 0; r < 4; ++r)
        outf[(size_t)(m + r) * ldo + n] = acc[i][j][r];
    }
  }
}

// ------------------------- logsumexp over K=72 ------------------------------
__global__ void lse_kernel(const float* __restrict__ Z, const float* __restrict__ b_lin,
                           float* __restrict__ lseout) {
  int row = blockIdx.x * 4 + (threadIdx.x >> 6);
  int l = threadIdx.x & 63;
  const float* z = Z + (size_t)row * 128;
  float v0 = (l < 72) ? z[l] + b_lin[l] : NEGF;
  float v1 = (l < 8) ? z[l + 64] + b_lin[l + 64] : NEGF;
  float m = fmaxf(v0, v1);
#pragma unroll
  for (int o = 32; o; o >>= 1) m = fmaxf(m, __shfl_xor(m, o, 64));
  float s = ((l < 72) ? __expf(v0 - m) : 0.f) + ((l < 8) ? __expf(v1 - m) : 0.f);
#pragma unroll
  for (int o = 32; o; o >>= 1) s += __shfl_xor(s, o, 64);
  if (l == 0) lseout[row] = m + __logf(s);
}

// ------------------------------ CTC forward ---------------------------------
// One wave per batch; 4 alpha/lane; depth-8 register-ring em prefetch
// (t-loop unrolled x8 so ring indices are compile-time).
__global__ void ctc_kernel(const float* __restrict__ Z, const float* __restrict__ lse,
                           const float* __restrict__ b_lin,
                           const int* __restrict__ labels, const int* __restrict__ inlen,
                           const int* __restrict__ lablen, float* __restrict__ num) {
  const int b = blockIdx.x;
  const int lane = threadIdx.x;          // 64
  __shared__ int ext[200];
  __shared__ float afin[200];

  for (int s = lane; s < 200; s += 64)
    ext[s] = (s < 193 && (s & 1)) ? labels[b * 96 + (s >> 1)] : 0;
  __syncthreads();

  const int L = lablen[b], len = inlen[b];
  const int Send = 2 * L + 1;
  const float* Zb = Z + (size_t)b * 1024 * 128;
  const float* lsb = lse + (size_t)b * 1024;

  float a[4];
  int   e[4];
  float bl[4];
  bool  skp[4], val[4];
#pragma unroll
  for (int j = 0; j < 4; ++j) {
    const int s = lane * 4 + j;
    e[j]   = (s < 193) ? ext[s] : 0;
    val[j] = (s < Send) && (s < 193);
    skp[j] = (s < 193) && (s & 1) && (s >= 2) && (ext[s] != ext[s - 2]);
    bl[j]  = b_lin[e[j]];
  }
  {
    const float ls0 = lsb[0];
#pragma unroll
    for (int j = 0; j < 4; ++j) {
      const int s = lane * 4 + j;
      a[j] = (s <= 1 && val[j]) ? (Zb[e[j]] + bl[j] - ls0) : NEGF;
    }
  }

  // one alpha step given em/ls for this t
  auto step = [&](const float em0, const float em1, const float em2, const float em3,
                  const float lst) {
    const float emv[4] = {em0, em1, em2, em3};
    float p3 = __shfl_up(a[3], 1, 64);
    float p2 = __shfl_up(a[2], 1, 64);
    if (lane == 0) { p3 = NEGF; p2 = NEGF; }
    const float x2[4] = {p3, a[0], a[1], a[2]};
    const float x3[4] = {p2, p3, a[0], a[1]};
#pragma unroll
    for (int j = 0; j < 4; ++j) {
      const float xa = a[j], xb = x2[j];
      const float xc = skp[j] ? x3[j] : NEGF;
      const float m = fmaxf(xa, fmaxf(xb, xc));
      const float sum = __expf(xa - m) + __expf(xb - m) + __expf(xc - m);
      const float nv = m + __logf(sum) + emv[j] + bl[j] - lst;
      a[j] = val[j] ? nv : NEGF;
    }
  };

  // depth-8 register ring (slots fixed at compile time via x8 unroll)
  float emr[8][4];
  float lsr[8];
#pragma unroll
  for (int d = 1; d <= 8; ++d) {
    const int r = (d < len) ? d : (len - 1);
    const float* zr = Zb + (size_t)r * 128;
#pragma unroll
    for (int j = 0; j < 4; ++j) emr[d & 7][j] = zr[e[j]];
    lsr[d & 7] = lsb[r];
  }

  int t = 1;
  for (; t + 8 <= len; t += 8) {
#pragma unroll
    for (int k = 0; k < 8; ++k) {
      const int slot = (1 + k) & 7;        // t == 1 (mod 8)
      const float e0 = emr[slot][0], e1 = emr[slot][1],
                  e2 = emr[slot][2], e3 = emr[slot][3];
      const float lst = lsr[slot];
      const int tp = t + k + 8;
      if (tp < len) {
        const float* zr = Zb + (size_t)tp * 128;
#pragma unroll
        for (int j = 0; j < 4; ++j) emr[slot][j] = zr[e[j]];
        lsr[slot] = lsb[tp];
      }
      step(e0, e1, e2, e3, lst);
    }
  }
  for (; t < len; ++t) {                   // tail: direct loads
    const float* zr = Zb + (size_t)t * 128;
    step(zr[e[0]], zr[e[1]], zr[e[2]], zr[e[3]], lsb[t]);
  }

#pragma unroll
  for (int j = 0; j < 4; ++j) {
    const int s = lane * 4 + j;
    if (s < 193) afin[s] = a[j];
  }
  __syncthreads();
  if (lane == 0) {
    const float aL = afin[2 * L], aLm1 = afin[2 * L - 1];
    const float m = fmaxf(aL, aLm1);
    num[b] = m + __logf(__expf(aL - m) + __expf(aLm1 - m));
  }
}

__global__ void final_kernel(const float* __restrict__ num, float* __restrict__ out) {
  int l = threadIdx.x;  // 64
  float v = -1.1f * num[l];
#pragma unroll
  for (int o = 32; o; o >>= 1) v += __shfl_xor(v, o, 64);
  if (l == 0) out[0] = v * (1.f / 64.f);
}

__global__ void sentinel_kernel(float* __restrict__ out, float code) { out[0] = code; }

// ------------------------------ launcher ------------------------------------
extern "C" void kernel_launch(void* const* d_in, const int* in_sizes, int n_in,
                              void* d_out, int out_size, void* d_ws, size_t ws_size,
                              hipStream_t stream) {
  (void)in_sizes; (void)n_in; (void)out_size;

  const float* logits   = (const float*)d_in[0];
  const int*   labels   = (const int*)d_in[1];
  const int*   in_lens  = (const int*)d_in[2];
  const int*   lab_lens = (const int*)d_in[3];
  const float* Wih0     = (const float*)d_in[4];
  const float* Whh0     = (const float*)d_in[5];
  const float* b0       = (const float*)d_in[6];
  const float* Wih      = (const float*)d_in[7];
  const float* Whh      = (const float*)d_in[8];
  const float* bb       = (const float*)d_in[9];
  const float* W_lin    = (const float*)d_in[10];
  const float* b_lin    = (const float*)d_in[11];

  const size_t NEED = (size_t)224 * 1024 * 1024;
  if (ws_size < NEED) {
    sentinel_kernel<<<1, 1, 0, stream>>>((float*)d_out, -(float)(ws_size >> 20));
    return;
  }

  char* ws = (char*)d_ws;
  size_t off = 0;
  auto alloc = [&](size_t bytes) -> char* {
    char* p = ws + off;
    off += (bytes + 255) & ~(size_t)255;
    return p;
  };
  f16*      Xa     = (f16*)alloc((size_t)65536 * 640 * 2);        // 83.9 MB
  f16*      Xb     = (f16*)alloc((size_t)65536 * 640 * 2);        // 83.9 MB
  f16*      gxc    = (f16*)alloc((size_t)2 * 64 * CT * 1280 * 2); // 41.9 MB
  f16*      Wt0    = (f16*)alloc((size_t)2560 * 128 * 2);
  f16*      Wt12   = (f16*)alloc((size_t)2 * 2560 * 640 * 2);
  f16*      WtL    = (f16*)alloc((size_t)128 * 640 * 2);
  uint32_t* whh16  = (uint32_t*)alloc((size_t)6 * 2 * 200 * 512 * 4);
  float*    lseb   = (float*)alloc((size_t)65536 * 4);
  float*    num    = (float*)alloc(64 * 4);
  uint32_t* xq     = (uint32_t*)alloc((size_t)512 * 160 * 4);
  f16*      hsave  = (f16*)alloc((size_t)128 * 320 * 2);
  float*    csave  = (float*)alloc((size_t)256 * 160 * 4);
  // aliases (disjoint lifetimes)
  f16*      A0     = Xb;           // dead after layer 0; Xb first written layer 1
  float*    Z      = (float*)gxc;  // gxc dead after layer-2 scan

  hipMemsetAsync(xq, 0, (size_t)512 * 160 * 4, stream);

  conv_logits<<<32768, 256, 0, stream>>>(logits, A0);
  conv_wt0<<<1280, 256, 0, stream>>>(Wih0, Wt0);
  conv_copy<<<12800, 256, 0, stream>>>(Wih, Wt12, 3276800);
  conv_wtl<<<320, 256, 0, stream>>>(W_lin, WtL);
  conv_whh<<<4800, 256, 0, stream>>>(Whh0, Whh, whh16);

  // layer 0: A0 -> Xa
  for (int c = 0; c < 1024 / CT; ++c) {
    gemm_chunk<<<dim3(5, 128), 256, 0, stream>>>(A0, Wt0, gxc, in_lens, 128, 4, c);
    lstm_scan_chunk<<<256, 512, 0, stream>>>(whh16, gxc, b0, in_lens, Xa, xq,
                                             hsave, csave, 0, c);
  }
  // layer 1: Xa -> Xb
  for (int c = 0; c < 1024 / CT; ++c) {
    gemm_chunk<<<dim3(5, 128), 256, 0, stream>>>(Xa, Wt12, gxc, in_lens, 640, 20, c);
    lstm_scan_chunk<<<256, 512, 0, stream>>>(whh16, gxc, bb, in_lens, Xb, xq,
                                             hsave, csave, 1, c);
  }
  // layer 2: Xb -> Xa
  for (int c = 0; c < 1024 / CT; ++c) {
    gemm_chunk<<<dim3(5, 128), 256, 0, stream>>>(Xb, Wt12 + (size_t)2560 * 640, gxc,
                                                 in_lens, 640, 20, c);
    lstm_scan_chunk<<<256, 512, 0, stream>>>(whh16, gxc, bb + 2560, in_lens, Xa, xq,
                                             hsave, csave, 2, c);
  }
  // projection: Xa -> Z (f32)
  gemm_proj<<<dim3(1, 512), 256, 0, stream>>>(Xa, WtL, Z, 640, 20, 128);

  lse_kernel<<<16384, 256, 0, stream>>>(Z, b_lin, lseb);
  ctc_kernel<<<64, 64, 0, stream>>>(Z, lseb, b_lin, labels, in_lens, lab_lens, num);
  final_kernel<<<1, 64, 0, stream>>>(num, (float*)d_out);
}

// Round 8
// 9017.635 us; speedup vs baseline: 1.0091x; 1.0091x over previous
//
#include <hip/hip_runtime.h>
#include <cstdint>
#include <cstddef>

// ---------------------------------------------------------------------------
// CTC-CRF BLSTM pipeline for MI355X.  B=64 T=1024 IDIM=120 HDIM=320 K=72
// den == 0 analytically; batch sort is a no-op under the batch mean. Skipped.
//
// R8 deltas vs R7 (9.10 ms):
//  - gemm: XOR-swizzled LDS staging (source-permuted k-chunks, since
//    global_load_lds pins slot=lane) kills the 8-way ds_read_b128 bank
//    conflict (SQ_LDS_BANK_CONFLICT 2.46M measured R7).
//  - ctc: emissions pre-gathered (parallel emz kernel) into contiguous
//    f16 rows emc[b][t][200] (aliases dead Xa); ctc loads 8B/lane with a
//    depth-4 ring that actually fits in VGPRs (R7's depth-8 ring spilled:
//    VGPR_Count=44 < ring size).
// ---------------------------------------------------------------------------

typedef _Float16 f16;
typedef _Float16 h2v   __attribute__((ext_vector_type(2)));
typedef _Float16 f16x4v __attribute__((ext_vector_type(4)));
typedef _Float16 f16x8 __attribute__((ext_vector_type(8)));
typedef float    f32x4 __attribute__((ext_vector_type(4)));
typedef uint32_t u32x4 __attribute__((ext_vector_type(4)));

#define NEGF (-1e30f)
#define CT 128

__device__ __forceinline__ float dot2f(h2v a, h2v b, float c) {
#if __has_builtin(__builtin_amdgcn_fdot2)
  return __builtin_amdgcn_fdot2(a, b, c, false);
#else
  return c + (float)a.x * (float)b.x + (float)a.y * (float)b.y;
#endif
}

__device__ __forceinline__ float fast_rcp(float x) {
#if __has_builtin(__builtin_amdgcn_rcpf)
  return __builtin_amdgcn_rcpf(x);
#else
  return 1.f / x;
#endif
}
__device__ __forceinline__ float fsigm(float x) { return fast_rcp(1.f + __expf(-x)); }
__device__ __forceinline__ float ftanh(float x) { return 1.f - 2.f * fast_rcp(1.f + __expf(2.f * x)); }

__device__ __forceinline__ void stage16(f16* lds, const f16* g) {
#if __has_builtin(__builtin_amdgcn_global_load_lds)
  __builtin_amdgcn_global_load_lds(
      (const __attribute__((address_space(1))) uint32_t*)g,
      (__attribute__((address_space(3))) uint32_t*)lds, 16, 0, 0);
#else
  int lane = threadIdx.x & 63;
  *(f16x8*)&lds[lane * 8] = *(const f16x8*)g;
#endif
}

// ---------------------------- convert kernels ------------------------------

__global__ void conv_logits(const float* __restrict__ src, f16* __restrict__ dst) {
  int idx = blockIdx.x * 256 + threadIdx.x;      // < 65536*128
  int row = idx >> 7, k = idx & 127;
  dst[idx] = (f16)((k < 120) ? src[(size_t)row * 120 + k] : 0.f);
}

__global__ void conv_wt0(const float* __restrict__ w, f16* __restrict__ dst) {
  int idx = blockIdx.x * 256 + threadIdx.x;      // < 2560*128
  int n = idx >> 7, k = idx & 127;
  dst[idx] = (f16)((k < 120) ? w[(size_t)n * 120 + k] : 0.f);
}

__global__ void conv_copy(const float* __restrict__ src, f16* __restrict__ dst, int count) {
  int idx = blockIdx.x * 256 + threadIdx.x;
  if (idx < count) dst[idx] = (f16)src[idx];
}

__global__ void conv_wtl(const float* __restrict__ w, f16* __restrict__ dst) {
  int idx = blockIdx.x * 256 + threadIdx.x;      // < 128*640
  int n = idx / 640, k = idx % 640;
  dst[idx] = (f16)((n < 72) ? w[(size_t)n * 640 + k] : 0.f);
}

// Whh -> pair-packed scan layout (same as R6/R7).
__global__ void conv_whh(const float* __restrict__ whh0, const float* __restrict__ whh,
                         uint32_t* __restrict__ dst) {
  int o = blockIdx.x * 256 + threadIdx.x;        // < 6*2*200*512 = 1228800
  int tid = o & 511;
  int g  = o >> 9;
  int j  = g % 40;
  int g2 = g / 40;
  int i  = g2 % 5;
  int g3 = g2 / 5;                               // 0..11
  int hf = g3 & 1, slot = g3 >> 1;               // slot = layer*2+dir
  int tau = i * 512 + tid;
  int lr = tau >> 2, kq = tau & 3;
  int gate = lr / 160, u = lr - gate * 160;
  int r = gate * 320 + hf * 160 + u;
  int k = kq * 80 + j * 2;
  const float* srcm = (slot < 2) ? (whh0 + ((size_t)slot * 1280 + r) * 320)
                                 : (whh  + ((size_t)(slot - 2) * 1280 + r) * 320);
  f16 lo = (f16)srcm[k], hi = (f16)srcm[k + 1];
  dst[o] = (uint32_t)__builtin_bit_cast(unsigned short, lo) |
           ((uint32_t)__builtin_bit_cast(unsigned short, hi) << 16);
}

// --------------------- gather-GEMM for one time chunk ----------------------
// Grid (5, 128): 256-wide N-supertile, y = dir*64 + b. M = 128 steps.
// LDS tiles use a source-permuted XOR swizzle: slot cs of row r holds global
// k-chunk (cs + (r>>1)) & 3, so ds_read_b128 bank-groups spread 2-way (free).
__global__ __launch_bounds__(256)
void gemm_chunk(const f16* __restrict__ A, const f16* __restrict__ W,
                f16* __restrict__ gxc, const int* __restrict__ lens,
                int lda, int kTiles, int c0) {
  __shared__ __align__(16) f16 As[128 * 32];
  __shared__ __align__(16) f16 Ws[2][128 * 32];
  const int tid = threadIdx.x;
  const int lane = tid & 63, wid = tid >> 6;
  const int wm = wid >> 1, wn = wid & 1;
  const int dir = blockIdx.y >> 6, b = blockIdx.y & 63;
  const int n0 = blockIdx.x * 256;
  const int r_base = lane >> 2;                              // 0..15
  const int chs = ((((lane & 3) + (r_base >> 1)) & 3)) * 8;  // swizzled SRC k-chunk
  const int len = lens[b];

  f32x4 acc[4][8] = {};

  for (int kt = 0; kt < kTiles; ++kt) {
    const int k0 = kt * 32;
    __syncthreads();
#pragma unroll
    for (int hh = 0; hh < 2; ++hh) {
      const int c = wid * 2 + hh;
      const int j = c * 16 + r_base;                     // step within chunk
      const int s = c0 * CT + j;
      const int tt = dir ? ((s < len) ? (len - 1 - s) : s) : s;
      stage16(&As[c * 512], A + (size_t)(b * 1024 + tt) * lda + k0 + chs);
    }
#pragma unroll
    for (int hh = 0; hh < 4; ++hh) {
      const int c = wid * 4 + hh;                        // 0..15
      const int tile = c >> 3, cc = c & 7;
      stage16(&Ws[tile][cc * 512],
              W + (size_t)(dir * 1280 + n0 + tile * 128 + cc * 16 + r_base) * lda + k0 + chs);
    }
    __syncthreads();

    const int q = lane >> 4;                 // MFMA k-chunk
    const int l15 = lane & 15;
    const int cs = (q - (l15 >> 1)) & 3;     // swizzled slot holding chunk q
    const int rofs = l15 * 32 + cs * 8;      // f16 units within a 16-row chunk
    f16x8 av[4], wv0[4], wv1[4];
#pragma unroll
    for (int i = 0; i < 4; ++i)
      av[i] = *(const f16x8*)&As[(wm * 4 + i) * 512 + rofs];
#pragma unroll
    for (int i = 0; i < 4; ++i) {
      wv0[i] = *(const f16x8*)&Ws[0][(wn * 4 + i) * 512 + rofs];
      wv1[i] = *(const f16x8*)&Ws[1][(wn * 4 + i) * 512 + rofs];
    }
#pragma unroll
    for (int i = 0; i < 4; ++i)
#pragma unroll
      for (int j = 0; j < 4; ++j) {
        acc[i][j]     = __builtin_amdgcn_mfma_f32_16x16x32_f16(av[i], wv0[j], acc[i][j], 0, 0, 0);
        acc[i][4 + j] = __builtin_amdgcn_mfma_f32_16x16x32_f16(av[i], wv1[j], acc[i][4 + j], 0, 0, 0);
      }
  }

  const int r0 = (lane >> 4) * 4, cn = lane & 15;
  const size_t obase = (size_t)(dir * 64 + b) * CT;
#pragma unroll
  for (int i = 0; i < 4; ++i) {
    const int m = wm * 64 + i * 16 + r0;
#pragma unroll
    for (int j = 0; j < 4; ++j) {
      const int n = n0 + wn * 64 + j * 16 + cn;
#pragma unroll
      for (int r = 0; r < 4; ++r) {
        gxc[(obase + m + r) * 1280 + n]       = (f16)acc[i][j][r];
        gxc[(obase + m + r) * 1280 + n + 128] = (f16)acc[i][4 + j][r];
      }
    }
  }
}

// ------------------------- LSTM scan (one chunk) ---------------------------
// (unchanged from R7: forced-resident weights, concurrent poll, fast gates)
__global__ void __launch_bounds__(512)
__attribute__((amdgpu_waves_per_eu(2, 2)))
lstm_scan_chunk(const volatile uint32_t* wbuf,      // NOT restrict: may alias
                const f16* __restrict__ gxc,        // [2*64*CT][1280]
                const float* __restrict__ bias,     // [2][1280] this layer
                const int* __restrict__ lens,
                f16* xnext,                         // [65536][640] (no restrict)
                uint32_t* xq,                       // [512][160] tagged words
                f16* hsave,                         // [128][320]
                float* csave,                       // [256][160]
                int layer, int c0) {
  const int wg = blockIdx.x;
  const int half = wg >> 7;
  const int bd = wg & 127;
  const int b = bd >> 1, dir = bd & 1;
  const int tid = threadIdx.x;

  __shared__ __align__(16) f16 hbuf[320];
  __shared__ float ylds[640];
  __shared__ __align__(16) f16 hstage[64 * 160];   // 20 KB ring

  h2v w[5][40];
  {
    const volatile uint32_t* wb =
        wbuf + (size_t)((layer * 2 + dir) * 2 + half) * 200 * 512;
#pragma unroll
    for (int i = 0; i < 5; ++i)
#pragma unroll
      for (int j = 0; j < 40; ++j) {
        uint32_t v = wb[(i * 40 + j) * 512 + tid];
        w[i][j] = __builtin_bit_cast(h2v, v);
      }
  }
  if (tid < 320) hbuf[tid] = (c0 == 0) ? (f16)0.f : hsave[bd * 320 + tid];

  const int len = lens[b];
  const int kq = tid & 3;
  const int qi = tid >> 2;
  const int gu = half * 160 + tid;               // valid when tid<160
  float c_state = 0.f;
  float bi = 0.f, bff = 0.f, bg = 0.f, bo = 0.f;
  if (tid < 160) {
    if (c0 > 0) c_state = csave[wg * 160 + tid];
    const float* bp = bias + dir * 1280 + gu;
    bi = bp[0]; bff = bp[320]; bg = bp[640]; bo = bp[960];
  }
  __syncthreads();

  const size_t grow0 = (size_t)(dir * 64 + b) * CT;

  float gxi = 0.f, gxf = 0.f, gxg = 0.f, gxo = 0.f;
  if (tid < 160) {
    const f16* gp = gxc + grow0 * 1280 + gu;
    gxi = (float)gp[0]; gxf = (float)gp[320]; gxg = (float)gp[640]; gxo = (float)gp[960];
  }

  for (int tl = 0; tl < CT; ++tl) {
    const int s = c0 * CT + tl;
    const uint32_t tag = (uint32_t)(layer * 1024 + s + 1);

    float nxi = 0.f, nxf = 0.f, nxg = 0.f, nxo = 0.f;
    if (tid < 160 && tl + 1 < CT) {
      const f16* gp = gxc + (grow0 + tl + 1) * 1280 + gu;
      nxi = (float)gp[0]; nxf = (float)gp[320]; nxg = (float)gp[640]; nxo = (float)gp[960];
    }

    // ---- y = Whh_half . h  (all threads, b128 LDS reads; broadcast-free) ----
    float a0 = 0.f, a1 = 0.f, a2 = 0.f, a3 = 0.f, a4 = 0.f;
    {
      const u32x4* h4 = (const u32x4*)hbuf;
#pragma unroll
      for (int jb = 0; jb < 5; ++jb) {
        u32x4 p = h4[kq * 10 + jb * 2];
        u32x4 q = h4[kq * 10 + jb * 2 + 1];
        h2v hr[8];
#pragma unroll
        for (int j = 0; j < 4; ++j) hr[j] = __builtin_bit_cast(h2v, p[j]);
#pragma unroll
        for (int j = 0; j < 4; ++j) hr[4 + j] = __builtin_bit_cast(h2v, q[j]);
#pragma unroll
        for (int j = 0; j < 8; ++j) {
          a0 = dot2f(w[0][jb * 8 + j], hr[j], a0);
          a1 = dot2f(w[1][jb * 8 + j], hr[j], a1);
          a2 = dot2f(w[2][jb * 8 + j], hr[j], a2);
          a3 = dot2f(w[3][jb * 8 + j], hr[j], a3);
          a4 = dot2f(w[4][jb * 8 + j], hr[j], a4);
        }
      }
    }
    {
      float av[5] = {a0, a1, a2, a3, a4};
#pragma unroll
      for (int i = 0; i < 5; ++i) {
        float v = av[i];
        v += __shfl_xor(v, 1, 64);
        v += __shfl_xor(v, 2, 64);
        if (kq == 0) ylds[i * 128 + qi] = v;
      }
    }

    if ((tl & 31) == 0 && tl > 0) {
      const int tw = tl - 32;
#pragma unroll
      for (int it = 0; it < 2; ++it) {
        const int slot = it * 512 + tid;
        if (slot < 640) {
          const int r = (int)(((unsigned)slot * 52429u) >> 20);  // slot/20
          const int j = slot - r * 20;
          const int sp = c0 * CT + tw + r;
          const int ttp = dir ? ((sp < len) ? (len - 1 - sp) : sp) : sp;
          f16x8 v = *(const f16x8*)&hstage[((tw + r) & 63) * 160 + j * 8];
          *(f16x8*)&xnext[(size_t)(b * 1024 + ttp) * 640 + dir * 320 + half * 160 + j * 8] = v;
        }
      }
    }
    __syncthreads();                              // B1: ylds ready

    if (tid < 160) {
      const int u = tid;
      float pi = ylds[u]       + gxi + bi;
      float pf = ylds[160 + u] + gxf + bff;
      float pg = ylds[320 + u] + gxg + bg;
      float po = ylds[480 + u] + gxo + bo;
      float ig = fsigm(pi);
      float fg = fsigm(pf);
      float gg = ftanh(pg);
      float og = fsigm(po);
      c_state = fg * c_state + ig * gg;
      float hv = og * ftanh(c_state);
      const f16 hh = (f16)hv;
      const uint32_t word = (tag << 16) |
                            (uint32_t)__builtin_bit_cast(unsigned short, hh);
      __hip_atomic_exchange(&xq[((bd * 2 + half) * 2 + (s & 1)) * 160 + u], word,
                            __ATOMIC_RELAXED, __HIP_MEMORY_SCOPE_AGENT);
      hbuf[gu] = hh;
      hstage[(tl & 63) * 160 + u] = hh;
    } else if (tid >= 256 && tid < 416) {
      const int u = tid - 256;
      uint32_t pw;
      int spins = 0;
      do {
        pw = __hip_atomic_fetch_add(&xq[((bd * 2 + (1 - half)) * 2 + (s & 1)) * 160 + u],
                                    0u, __ATOMIC_RELAXED, __HIP_MEMORY_SCOPE_AGENT);
      } while ((pw >> 16) != tag && ++spins < 30000);
      hbuf[(1 - half) * 160 + u] =
          __builtin_bit_cast(f16, (unsigned short)(pw & 0xffffu));
    }
    __syncthreads();                              // B2: hbuf ready for next dot

    gxi = nxi; gxf = nxf; gxg = nxg; gxo = nxo;
  }

  {
    const int tw = CT - 32;
#pragma unroll
    for (int it = 0; it < 2; ++it) {
      const int slot = it * 512 + tid;
      if (slot < 640) {
        const int r = (int)(((unsigned)slot * 52429u) >> 20);
        const int j = slot - r * 20;
        const int sp = c0 * CT + tw + r;
        const int ttp = dir ? ((sp < len) ? (len - 1 - sp) : sp) : sp;
        f16x8 v = *(const f16x8*)&hstage[((tw + r) & 63) * 160 + j * 8];
        *(f16x8*)&xnext[(size_t)(b * 1024 + ttp) * 640 + dir * 320 + half * 160 + j * 8] = v;
      }
    }
  }
  if (tid < 160) {
    hsave[bd * 320 + gu] = hbuf[gu];
    csave[wg * 160 + tid] = c_state;
  }
}

// ---------------------- projection GEMM (f32 out) --------------------------
__global__ __launch_bounds__(256)
void gemm_proj(const f16* __restrict__ A, const f16* __restrict__ W,
               float* __restrict__ outf, int lda, int kTiles, int ldo) {
  __shared__ __align__(16) f16 As[128 * 32];
  __shared__ __align__(16) f16 Ws[128 * 32];
  const int tid = threadIdx.x;
  const int lane = tid & 63, wid = tid >> 6;
  const int wm = wid >> 1, wn = wid & 1;
  const int m0 = blockIdx.y * 128, n0 = blockIdx.x * 128;
  const int r_base = lane >> 2;
  const int chs = ((((lane & 3) + (r_base >> 1)) & 3)) * 8;  // swizzled SRC chunk

  f32x4 acc[4][4] = {};

  for (int kt = 0; kt < kTiles; ++kt) {
    const int k0 = kt * 32;
    __syncthreads();
#pragma unroll
    for (int hh = 0; hh < 2; ++hh) {
      const int c = wid * 2 + hh;
      stage16(&As[c * 512], A + (size_t)(m0 + c * 16 + r_base) * lda + k0 + chs);
      stage16(&Ws[c * 512], W + (size_t)(n0 + c * 16 + r_base) * lda + k0 + chs);
    }
    __syncthreads();

    const int q = lane >> 4;
    const int l15 = lane & 15;
    const int cs = (q - (l15 >> 1)) & 3;
    const int rofs = l15 * 32 + cs * 8;
    f16x8 av[4], wv[4];
#pragma unroll
    for (int i = 0; i < 4; ++i)
      av[i] = *(const f16x8*)&As[(wm * 4 + i) * 512 + rofs];
#pragma unroll
    for (int i = 0; i < 4; ++i)
      wv[i] = *(const f16x8*)&Ws[(wn * 4 + i) * 512 + rofs];
#pragma unroll
    for (int i = 0; i < 4; ++i)
#pragma unroll
      for (int j = 0; j < 4; ++j)
        acc[i][j] = __builtin_amdgcn_mfma_f32_16x16x32_f16(av[i], wv[j], acc[i][j], 0, 0, 0);
  }

  const int r0 = (lane >> 4) * 4, cn = lane & 15;
#pragma unroll
  for (int i = 0; i < 4; ++i) {
    const int m = m0 + wm * 64 + i * 16 + r0;
#pragma unroll
    for (int j = 0; j < 4; ++j) {
      const int n = n0 + wn * 64 + j * 16 + cn;
#pragma unroll
      for (int r = 0; r < 4; ++r)
        outf[(size_t)(m + r) * ldo + n] = acc[i][j][r];
    }
  }
}

// ------------------------- logsumexp over K=72 ------------------------------
__global__ void lse_kernel(const float* __restrict__ Z, const float* __restrict__ b_lin,
                           float* __restrict__ lseout) {
  int row = blockIdx.x * 4 + (threadIdx.x >> 6);
  int l = threadIdx.x & 63;
  const float* z = Z + (size_t)row * 128;
  float v0 = (l < 72) ? z[l] + b_lin[l] : NEGF;
  float v1 = (l < 8) ? z[l + 64] + b_lin[l + 64] : NEGF;
  float m = fmaxf(v0, v1);
#pragma unroll
  for (int o = 32; o; o >>= 1) m = fmaxf(m, __shfl_xor(m, o, 64));
  float s = ((l < 72) ? __expf(v0 - m) : 0.f) + ((l < 8) ? __expf(v1 - m) : 0.f);
#pragma unroll
  for (int o = 32; o; o >>= 1) s += __shfl_xor(s, o, 64);
  if (l == 0) lseout[row] = m + __logf(s);
}

// --------------- emission pre-gather: emc[b][t][s] (f16) -------------------
// emc = Z[t][ext[s]] + b_lin[ext[s]] - lse[t]. Fully parallel over (b,t).
__global__ void emz_kernel(const float* __restrict__ Z, const float* __restrict__ lse,
                           const float* __restrict__ b_lin,
                           const int* __restrict__ labels,
                           f16* __restrict__ emc) {
  const int b = blockIdx.y;
  const int t0 = blockIdx.x * 4;
  const int tid = threadIdx.x;   // 256
  __shared__ int ext[200];
  __shared__ float bls[200];
  if (tid < 200) {
    int e = (tid < 193 && (tid & 1)) ? labels[b * 96 + (tid >> 1)] : 0;
    ext[tid] = e;
    bls[tid] = b_lin[e];
  }
  __syncthreads();
#pragma unroll
  for (int dt = 0; dt < 4; ++dt) {
    const int t = t0 + dt;
    const float lst = lse[b * 1024 + t];
    const float* zr = Z + ((size_t)(b * 1024 + t)) * 128;
    for (int s = tid; s < 200; s += 256)
      emc[((size_t)(b * 1024 + t)) * 200 + s] = (f16)(zr[ext[s]] + bls[s] - lst);
  }
}

// ------------------------------ CTC forward ---------------------------------
// One wave per batch; 4 alpha/lane; contiguous 8B/lane em loads, depth-4 ring.
__global__ void ctc_kernel(const f16* __restrict__ emc,
                           const int* __restrict__ labels, const int* __restrict__ inlen,
                           const int* __restrict__ lablen, float* __restrict__ num) {
  const int b = blockIdx.x;
  const int lane = threadIdx.x;          // 64
  __shared__ int ext[200];
  __shared__ float afin[200];

  for (int s = lane; s < 200; s += 64)
    ext[s] = (s < 193 && (s & 1)) ? labels[b * 96 + (s >> 1)] : 0;
  __syncthreads();

  const int L = lablen[b], len = inlen[b];
  const int Send = 2 * L + 1;
  const f16* eb = emc + (size_t)b * 1024 * 200;

  float a[4];
  bool  skp[4], val[4];
#pragma unroll
  for (int j = 0; j < 4; ++j) {
    const int s = lane * 4 + j;
    val[j] = (s < Send) && (s < 193);
    skp[j] = (s < 193) && (s & 1) && (s >= 2) && (ext[s] != ext[s - 2]);
  }
  {
    f16x4v e0 = *(const f16x4v*)&eb[lane * 4];   // t = 0
#pragma unroll
    for (int j = 0; j < 4; ++j) {
      const int s = lane * 4 + j;
      a[j] = (s <= 1 && val[j]) ? (float)e0[j] : NEGF;
    }
  }

  auto step = [&](f16x4v ev) {
    float p3 = __shfl_up(a[3], 1, 64);
    float p2 = __shfl_up(a[2], 1, 64);
    if (lane == 0) { p3 = NEGF; p2 = NEGF; }
    const float x2[4] = {p3, a[0], a[1], a[2]};
    const float x3[4] = {p2, p3, a[0], a[1]};
#pragma unroll
    for (int j = 0; j < 4; ++j) {
      const float xa = a[j], xb = x2[j];
      const float xc = skp[j] ? x3[j] : NEGF;
      const float m = fmaxf(xa, fmaxf(xb, xc));
      const float sum = __expf(xa - m) + __expf(xb - m) + __expf(xc - m);
      const float nv = m + __logf(sum) + (float)ev[j];
      a[j] = val[j] ? nv : NEGF;
    }
  };

  // depth-4 register ring (fits: 8 VGPRs)
  f16x4v ring[4];
#pragma unroll
  for (int d = 1; d <= 4; ++d) {
    const int r = (d < len) ? d : (len - 1);
    ring[d & 3] = *(const f16x4v*)&eb[(size_t)r * 200 + lane * 4];
  }

  int t = 1;
  for (; t + 4 <= len; t += 4) {
#pragma unroll
    for (int k = 0; k < 4; ++k) {
      const int slot = (1 + k) & 3;        // t == 1 (mod 4)
      f16x4v ev = ring[slot];
      const int tp = t + k + 4;
      if (tp < len)
        ring[slot] = *(const f16x4v*)&eb[(size_t)tp * 200 + lane * 4];
      step(ev);
    }
  }
  for (; t < len; ++t)
    step(*(const f16x4v*)&eb[(size_t)t * 200 + lane * 4]);

#pragma unroll
  for (int j = 0; j < 4; ++j) {
    const int s = lane * 4 + j;
    if (s < 193) afin[s] = a[j];
  }
  __syncthreads();
  if (lane == 0) {
    const float aL = afin[2 * L], aLm1 = afin[2 * L - 1];
    const float m = fmaxf(aL, aLm1);
    num[b] = m + __logf(__expf(aL - m) + __expf(aLm1 - m));
  }
}

__global__ void final_kernel(const float* __restrict__ num, float* __restrict__ out) {
  int l = threadIdx.x;  // 64
  float v = -1.1f * num[l];
#pragma unroll
  for (int o = 32; o; o >>= 1) v += __shfl_xor(v, o, 64);
  if (l == 0) out[0] = v * (1.f / 64.f);
}

__global__ void sentinel_kernel(float* __restrict__ out, float code) { out[0] = code; }

// ------------------------------ launcher ------------------------------------
extern "C" void kernel_launch(void* const* d_in, const int* in_sizes, int n_in,
                              void* d_out, int out_size, void* d_ws, size_t ws_size,
                              hipStream_t stream) {
  (void)in_sizes; (void)n_in; (void)out_size;

  const float* logits   = (const float*)d_in[0];
  const int*   labels   = (const int*)d_in[1];
  const int*   in_lens  = (const int*)d_in[2];
  const int*   lab_lens = (const int*)d_in[3];
  const float* Wih0     = (const float*)d_in[4];
  const float* Whh0     = (const float*)d_in[5];
  const float* b0       = (const float*)d_in[6];
  const float* Wih      = (const float*)d_in[7];
  const float* Whh      = (const float*)d_in[8];
  const float* bb       = (const float*)d_in[9];
  const float* W_lin    = (const float*)d_in[10];
  const float* b_lin    = (const float*)d_in[11];

  const size_t NEED = (size_t)224 * 1024 * 1024;
  if (ws_size < NEED) {
    sentinel_kernel<<<1, 1, 0, stream>>>((float*)d_out, -(float)(ws_size >> 20));
    return;
  }

  char* ws = (char*)d_ws;
  size_t off = 0;
  auto alloc = [&](size_t bytes) -> char* {
    char* p = ws + off;
    off += (bytes + 255) & ~(size_t)255;
    return p;
  };
  f16*      Xa     = (f16*)alloc((size_t)65536 * 640 * 2);        // 83.9 MB
  f16*      Xb     = (f16*)alloc((size_t)65536 * 640 * 2);        // 83.9 MB
  f16*      gxc    = (f16*)alloc((size_t)2 * 64 * CT * 1280 * 2); // 41.9 MB
  f16*      Wt0    = (f16*)alloc((size_t)2560 * 128 * 2);
  f16*      Wt12   = (f16*)alloc((size_t)2 * 2560 * 640 * 2);
  f16*      WtL    = (f16*)alloc((size_t)128 * 640 * 2);
  uint32_t* whh16  = (uint32_t*)alloc((size_t)6 * 2 * 200 * 512 * 4);
  float*    lseb   = (float*)alloc((size_t)65536 * 4);
  float*    num    = (float*)alloc(64 * 4);
  uint32_t* xq     = (uint32_t*)alloc((size_t)512 * 160 * 4);
  f16*      hsave  = (f16*)alloc((size_t)128 * 320 * 2);
  float*    csave  = (float*)alloc((size_t)256 * 160 * 4);
  // aliases (disjoint lifetimes)
  f16*      A0     = Xb;           // dead after layer 0; Xb first written layer 1
  float*    Z      = (float*)gxc;  // gxc dead after layer-2 scan
  f16*      emc    = Xa;           // Xa dead after gemm_proj

  hipMemsetAsync(xq, 0, (size_t)512 * 160 * 4, stream);

  conv_logits<<<32768, 256, 0, stream>>>(logits, A0);
  conv_wt0<<<1280, 256, 0, stream>>>(Wih0, Wt0);
  conv_copy<<<12800, 256, 0, stream>>>(Wih, Wt12, 3276800);
  conv_wtl<<<320, 256, 0, stream>>>(W_lin, WtL);
  conv_whh<<<4800, 256, 0, stream>>>(Whh0, Whh, whh16);

  // layer 0: A0 -> Xa
  for (int c = 0; c < 1024 / CT; ++c) {
    gemm_chunk<<<dim3(5, 128), 256, 0, stream>>>(A0, Wt0, gxc, in_lens, 128, 4, c);
    lstm_scan_chunk<<<256, 512, 0, stream>>>(whh16, gxc, b0, in_lens, Xa, xq,
                                             hsave, csave, 0, c);
  }
  // layer 1: Xa -> Xb
  for (int c = 0; c < 1024 / CT; ++c) {
    gemm_chunk<<<dim3(5, 128), 256, 0, stream>>>(Xa, Wt12, gxc, in_lens, 640, 20, c);
    lstm_scan_chunk<<<256, 512, 0, stream>>>(whh16, gxc, bb, in_lens, Xb, xq,
                                             hsave, csave, 1, c);
  }
  // layer 2: Xb -> Xa
  for (int c = 0; c < 1024 / CT; ++c) {
    gemm_chunk<<<dim3(5, 128), 256, 0, stream>>>(Xb, Wt12 + (size_t)2560 * 640, gxc,
                                                 in_lens, 640, 20, c);
    lstm_scan_chunk<<<256, 512, 0, stream>>>(whh16, gxc, bb + 2560, in_lens, Xa, xq,
                                             hsave, csave, 2, c);
  }
  // projection: Xa -> Z (f32)
  gemm_proj<<<dim3(1, 512), 256, 0, stream>>>(Xa, WtL, Z, 640, 20, 128);

  lse_kernel<<<16384, 256, 0, stream>>>(Z, b_lin, lseb);
  emz_kernel<<<dim3(256, 64), 256, 0, stream>>>(Z, lseb, b_lin, labels, emc);
  ctc_kernel<<<64, 64, 0, stream>>>(emc, labels, in_lens, lab_lens, num);
  final_kernel<<<1, 64, 0, stream>>>(num, (float*)d_out);
}